// Round 12
// baseline (3233.272 us; speedup 1.0000x reference)
//
#include <hip/hip_runtime.h>
#include <math.h>

#define BSZ 64
#define PLEN 128
#define HLEN 64
#define EDIM 300
#define HDIM 512
#define G4 2048   // 4*HDIM
#define NCLS 3

// spin guard: protocol bug degrades to wrong answer, not a hung container.
#define SPIN_CAP (1 << 18)

// 16-chunk 512-float vector layout: 16 chunks of 36 floats (32 data + 4 pad).
#define CR16 576
#define C16(f) ((((f) >> 5) * 36) + ((f) & 31))

__device__ __forceinline__ float sigf(float x) { return 1.0f / (1.0f + __expf(-x)); }
__device__ __forceinline__ float tanhfast(float x) { return 1.0f - 2.0f / (__expf(2.0f * x) + 1.0f); }

// relaxed agent-scope atomics: LLC-coherent, XCD-placement-independent
__device__ __forceinline__ unsigned long long aload64(const unsigned long long* p) {
    return __hip_atomic_load(p, __ATOMIC_RELAXED, __HIP_MEMORY_SCOPE_AGENT);
}
__device__ __forceinline__ void astore64(unsigned long long* p, unsigned long long v) {
    __hip_atomic_store(p, v, __ATOMIC_RELAXED, __HIP_MEMORY_SCOPE_AGENT);
}
__device__ __forceinline__ float aload32f(const float* p) {
    return __hip_atomic_load(p, __ATOMIC_RELAXED, __HIP_MEMORY_SCOPE_AGENT);
}
__device__ __forceinline__ void astore32f(float* p, float v) {
    __hip_atomic_store(p, v, __ATOMIC_RELAXED, __HIP_MEMORY_SCOPE_AGENT);
}
__device__ __forceinline__ unsigned long long fpack2(float lo, float hi) {
    float2 v = make_float2(lo, hi);
    return *(unsigned long long*)&v;
}
__device__ __forceinline__ float2 funpack2(unsigned long long u) {
    union { unsigned long long u; float2 f; } c; c.u = u; return c.f;
}

__global__ __launch_bounds__(256) void ws_zero(unsigned long long* p) {
    p[(size_t)blockIdx.x * 256 + threadIdx.x] = 0ull;
}

// ---------------------------------------------------------------------------
// input projection GEMM: out[m][row] = emb[toks[m]] . Wih[row] + bih[row]+bhh[row]
__global__ __launch_bounds__(256) void proj_kernel(
    const int* __restrict__ toks, const float* __restrict__ emb,
    const float* __restrict__ Wih, const float* __restrict__ bih,
    const float* __restrict__ bhh, float* __restrict__ out)
{
    __shared__ float es[32 * 100];
    __shared__ float wsh[64 * 100];
    __shared__ int tks[32];
    const int m0 = blockIdx.x * 32, r0 = blockIdx.y * 64;
    const int tid = threadIdx.x;
    const int tx = tid & 15, ty = tid >> 4;
    float acc[2][4] = {{0.f, 0.f, 0.f, 0.f}, {0.f, 0.f, 0.f, 0.f}};
    if (tid < 32) tks[tid] = toks[m0 + tid];
    __syncthreads();
    for (int kc = 0; kc < 3; kc++) {
        if (kc) __syncthreads();
        for (int i = tid; i < 800; i += 256) {
            int row = i / 25, k4 = i % 25;
            ((float4*)es)[i] = ((const float4*)(emb + (size_t)tks[row] * EDIM + kc * 100))[k4];
        }
        for (int i = tid; i < 1600; i += 256) {
            int row = i / 25, k4 = i % 25;
            ((float4*)wsh)[i] = ((const float4*)(Wih + (size_t)(r0 + row) * EDIM + kc * 100))[k4];
        }
        __syncthreads();
        const float4* e0 = (const float4*)es + ty * 25;
        const float4* e1 = e0 + 16 * 25;
        const float4* w0 = (const float4*)wsh + tx * 25;
#pragma unroll
        for (int k = 0; k < 25; k++) {
            float4 ea = e0[k], eb = e1[k];
#pragma unroll
            for (int j = 0; j < 4; j++) {
                float4 w = w0[k + j * 400];
                acc[0][j] += ea.x * w.x + ea.y * w.y + ea.z * w.z + ea.w * w.w;
                acc[1][j] += eb.x * w.x + eb.y * w.y + eb.z * w.z + eb.w * w.w;
            }
        }
    }
#pragma unroll
    for (int j = 0; j < 4; j++) {
        int rr = r0 + tx + j * 16;
        float bsum = bih[rr] + bhh[rr];
        out[(size_t)(m0 + ty) * G4 + rr]      = acc[0][j] + bsum;
        out[(size_t)(m0 + ty + 16) * G4 + rr] = acc[1][j] + bsum;
    }
}

// ---------------------------------------------------------------------------
// FUSED persistent kernel: 512 blocks x 256 threads, 2 blocks/CU.
// blocks 0..255  : LSTM role (R10 structure; outseq stores agent-scope and
//                  drained BEFORE dnH publish so consumers may read them).
// blocks 256..511: ATT role. Same XCD as its b-group (both roles map
//                  bg = blockIdx&7 -> XCD). During premise phase computes its
//                  a1 slice incrementally (Wy GEMV per step, gated on dnH);
//                  during layer-2 runs the 2-exchange attention recurrence,
//                  computing a2 locally from q_t via Wh GEMV.
// lstm NEVER waits on att: if co-residency fails, execution degrades to
// serial (correct), not deadlock. All polls SPIN_CAP-guarded.
__global__ __launch_bounds__(256, 2) void fused_coop(
    const float* __restrict__ xp, const float* __restrict__ xh,
    const float* __restrict__ Whh1, const float* __restrict__ Whh2,
    float* __restrict__ outp, float* __restrict__ outh,
    unsigned long long* __restrict__ hA, unsigned long long* __restrict__ hB,
    unsigned long long* __restrict__ hC, unsigned long long* __restrict__ hD,
    unsigned long long* __restrict__ doneH,
    float* __restrict__ a1b,
    const float* __restrict__ Wh, const float* __restrict__ Wr,
    const float* __restrict__ Wt, const float* __restrict__ Wy,
    const float* __restrict__ wv,
    unsigned long long* __restrict__ rA, unsigned long long* __restrict__ rB,
    unsigned long long* __restrict__ sPart,
    unsigned long long* __restrict__ dnS, unsigned long long* __restrict__ dnR)
{
    extern __shared__ __align__(16) float smem[];
    const int tid = threadIdx.x;

    if (blockIdx.x < 256) {
        // ==================== LSTM role ====================
        const int ug = blockIdx.x >> 3;
        const int bg = blockIdx.x & 7;
        const int u0 = ug * 16, b0 = bg * 8;
        const int rq = tid >> 4, cc = tid & 15;

        float* hst = smem;                 // 8*CR16
        float* gsm = smem + 8 * CR16;      // [64][9]

        float4 w4[32];
#pragma unroll
        for (int j = 0; j < 4; j++) {
            int rr = 4 * rq + j;
            const float4* src = (const float4*)(Whh1 +
                ((size_t)((rr >> 4) * HDIM + u0 + (rr & 15))) * HDIM) + cc * 8;
#pragma unroll
            for (int q = 0; q < 8; q++) w4[j * 8 + q] = src[q];
        }
        float creg = 0.0f;
        const int bbc = tid >> 4, uuc = tid & 15;
        unsigned long long* dn = doneH + bg * 32;

        for (int t = 0; t < PLEN + HLEN; t++) {
            const int layer2 = (t >= PLEN) ? 1 : 0;
            const int tloc = layer2 ? t - PLEN : t;
            const int T = layer2 ? HLEN : PLEN;
            const float* xproj = layer2 ? xh : xp;
            float* outseq = layer2 ? outh : outp;
            unsigned long long* wA = layer2 ? hC : hA;
            unsigned long long* wB = layer2 ? hD : hB;
            unsigned long long* hwr = (t & 1) ? wB : wA;
            const unsigned long long* hrd = (t & 1) ? wA : wB;

            float gi = 0.f, gf = 0.f, gg = 0.f, go = 0.f;
            if (tid < 128) {
                size_t xb = ((size_t)(b0 + bbc) * T + tloc) * G4 + u0 + uuc;
                gi = xproj[xb];        gf = xproj[xb + 512];
                gg = xproj[xb + 1024]; go = xproj[xb + 1536];
            }
            if (t == PLEN) {
#pragma unroll
                for (int j = 0; j < 4; j++) {
                    int rr = 4 * rq + j;
                    const float4* src = (const float4*)(Whh2 +
                        ((size_t)((rr >> 4) * HDIM + u0 + (rr & 15))) * HDIM) + cc * 8;
#pragma unroll
                    for (int q = 0; q < 8; q++) w4[j * 8 + q] = src[q];
                }
            }
            const bool have_h = (tloc != 0);
            if (have_h) {
                if (tid < 32) {
                    unsigned long long v = aload64(dn + tid);
                    int guard = 0;
                    while (!__all(v >= (unsigned long long)t)) {
                        if (++guard > SPIN_CAP) break;
                        __builtin_amdgcn_s_sleep(1);
                        if (v < (unsigned long long)t) v = aload64(dn + tid);
                    }
                }
                __syncthreads();
                __asm__ volatile("" ::: "memory");
                const unsigned long long* src = hrd + (size_t)b0 * 256;
                unsigned long long v[8];
#pragma unroll
                for (int i = 0; i < 8; i++) v[i] = aload64(src + tid + i * 256);
#pragma unroll
                for (int i = 0; i < 8; i++) {
                    int idx = tid + i * 256;
                    int bb = idx >> 8, j = idx & 255;
                    float2 f = funpack2(v[i]);
                    *(float2*)&hst[bb * CR16 + C16(2 * j)] = f;
                }
                __syncthreads();
#pragma unroll 1
                for (int bb = 0; bb < 8; bb++) {
                    const float* hb = &hst[bb * CR16 + cc * 36];
                    float a0 = 0.f, a1 = 0.f, a2 = 0.f, a3 = 0.f;
#pragma unroll
                    for (int q = 0; q < 8; q++) {
                        float4 hv = *(const float4*)(hb + 4 * q);
                        float4 x;
                        x = w4[q];      a0 += x.x * hv.x + x.y * hv.y + x.z * hv.z + x.w * hv.w;
                        x = w4[8 + q];  a1 += x.x * hv.x + x.y * hv.y + x.z * hv.z + x.w * hv.w;
                        x = w4[16 + q]; a2 += x.x * hv.x + x.y * hv.y + x.z * hv.z + x.w * hv.w;
                        x = w4[24 + q]; a3 += x.x * hv.x + x.y * hv.y + x.z * hv.z + x.w * hv.w;
                    }
#pragma unroll
                    for (int o = 1; o < 16; o <<= 1) {
                        a0 += __shfl_xor(a0, o);
                        a1 += __shfl_xor(a1, o);
                        a2 += __shfl_xor(a2, o);
                        a3 += __shfl_xor(a3, o);
                    }
                    if (cc == 0) {
                        gsm[(4 * rq + 0) * 9 + bb] = a0;
                        gsm[(4 * rq + 1) * 9 + bb] = a1;
                        gsm[(4 * rq + 2) * 9 + bb] = a2;
                        gsm[(4 * rq + 3) * 9 + bb] = a3;
                    }
                }
            }
            __syncthreads();
            if (tid < 128) {
                if (have_h) {
                    gi += gsm[uuc * 9 + bbc];
                    gf += gsm[(16 + uuc) * 9 + bbc];
                    gg += gsm[(32 + uuc) * 9 + bbc];
                    go += gsm[(48 + uuc) * 9 + bbc];
                }
                float cn = sigf(gf) * creg + sigf(gi) * tanhfast(gg);
                float hn = sigf(go) * tanhfast(cn);
                creg = cn;
                float pr = __shfl_xor(hn, 1);
                if ((uuc & 1) == 0)
                    astore64(hwr + (size_t)(b0 + bbc) * 256 + (u0 + uuc) / 2, fpack2(hn, pr));
                // outseq agent store BEFORE the drain: dnH certifies visibility
                astore32f(outseq + ((size_t)(b0 + bbc) * T + tloc) * HDIM + u0 + uuc, hn);
            }
            __asm__ volatile("s_waitcnt vmcnt(0)" ::: "memory");
            __syncthreads();
            if (tid == 0) astore64(&dn[ug], (unsigned long long)(t + 1));
        }
        return;
    }

    // ==================== ATT role ====================
    const int local = blockIdx.x - 256;
    const int ug = local >> 3;
    const int bg = local & 7;
    const int u0 = ug * 16, b0 = bg * 8;
    const int rp = tid >> 4, cc = tid & 15;   // GEMV: row, K-chunk
    const int ab = tid >> 5, aq = tid & 31;   // partial-s: batch, p-quad

    float* qst  = smem;                 // 8*CR16 (q_t / premise outp staging)
    float* rst  = smem + 4608;          // 8*CR16 (r staging)
    float* scst = smem + 9216;          // [8][132]
    float* a2sl = smem + 10272;         // [16][9]
    float* ttsl = smem + 10416;         // [16][9]
    float* wvs  = smem + 10560;         // 16
    float* psum = smem + 10576;         // 256

    float4 wh4[8], wr4[8], wt4[8];
    {
        const float4* sh = (const float4*)(Wh + (size_t)(u0 + rp) * HDIM) + cc * 8;
        const float4* sr = (const float4*)(Wr + (size_t)(u0 + rp) * HDIM) + cc * 8;
        const float4* st = (const float4*)(Wt + (size_t)(u0 + rp) * HDIM) + cc * 8;
#pragma unroll
        for (int q = 0; q < 8; q++) { wh4[q] = sh[q]; wr4[q] = sr[q]; wt4[q] = st[q]; }
    }
    if (tid < 16) wvs[tid] = wv[u0 + tid];

    unsigned long long* dnl = doneH + bg * 32;
    unsigned long long* myS = dnS + bg * 32;
    unsigned long long* myR = dnR + bg * 32;
    const int bbc = tid >> 4, uuc = tid & 15;

    // ---- premise phase: incremental a1 slice (gated on lstm's dnH)
    {
        float4 wy4[8];
        const float4* sy = (const float4*)(Wy + (size_t)(u0 + rp) * HDIM) + cc * 8;
#pragma unroll
        for (int q = 0; q < 8; q++) wy4[q] = sy[q];

        for (int p = 0; p < PLEN; p++) {
            if (tid < 32) {
                unsigned long long v = aload64(dnl + tid);
                int guard = 0;
                while (!__all(v >= (unsigned long long)(p + 1))) {
                    if (++guard > SPIN_CAP) break;
                    __builtin_amdgcn_s_sleep(1);
                    if (v < (unsigned long long)(p + 1)) v = aload64(dnl + tid);
                }
            }
            __syncthreads();
            __asm__ volatile("" ::: "memory");
            // stage outp[b0..7][p][:] (agent loads, LLC)
            {
                const unsigned long long* src =
                    (const unsigned long long*)(outp) + ((size_t)b0 * PLEN + p) * 256;
#pragma unroll
                for (int i = 0; i < 8; i++) {
                    int idx = tid + i * 256;
                    int bb = idx >> 8, j = idx & 255;
                    float2 f = funpack2(aload64(src + (size_t)bb * PLEN * 256 + j));
                    *(float2*)&qst[bb * CR16 + C16(2 * j)] = f;
                }
            }
            __syncthreads();
            // GEMV: a1[b][p][u0+rp] = Wy[u0+rp] . outp[b][p]
#pragma unroll 1
            for (int b = 0; b < 8; b++) {
                const float* qb = &qst[b * CR16 + cc * 36];
                float a = 0.f;
#pragma unroll
                for (int q = 0; q < 8; q++) {
                    float4 qv = *(const float4*)(qb + 4 * q);
                    float4 x = wy4[q];
                    a += x.x * qv.x + x.y * qv.y + x.z * qv.z + x.w * qv.w;
                }
#pragma unroll
                for (int o = 1; o < 16; o <<= 1) a += __shfl_xor(a, o);
                if (cc == 0)
                    a1b[((size_t)(b0 + b) * PLEN + p) * HDIM + u0 + rp] = a;
            }
            __syncthreads();   // qst reads done before next stage
        }
    }
    // reload own a1 slice into regs: thread (ab, aq): p=4aq..+3, h=u0..+15
    __asm__ volatile("s_waitcnt vmcnt(0)" ::: "memory");
    __syncthreads();
    float4 a1r[4][4];
#pragma unroll
    for (int pi = 0; pi < 4; pi++) {
        const float4* src = (const float4*)(a1b +
            ((size_t)(b0 + ab) * PLEN + 4 * aq + pi) * HDIM + u0);
#pragma unroll
        for (int k = 0; k < 4; k++) a1r[pi][k] = src[k];
    }

    // ---- attention recurrence (overlapped with lstm layer-2)
    for (int t = 0; t < HLEN; t++) {
        unsigned long long* rwr = (t & 1) ? rB : rA;
        const unsigned long long* rrd = (t & 1) ? rA : rB;
        unsigned long long* sp = sPart + ((size_t)((t & 1) * 8 + bg)) * 16384;

        // wait q_t = outh[:,t,:] (lstm layer-2 step t -> dnH = 129+t)
        if (tid < 32) {
            unsigned long long v = aload64(dnl + tid);
            int guard = 0;
            while (!__all(v >= (unsigned long long)(129 + t))) {
                if (++guard > SPIN_CAP) break;
                __builtin_amdgcn_s_sleep(1);
                if (v < (unsigned long long)(129 + t)) v = aload64(dnl + tid);
            }
        }
        // wait r_{t-1}
        if (t > 0 && tid < 32) {
            unsigned long long v = aload64(myR + tid);
            int guard = 0;
            while (!__all(v >= (unsigned long long)t)) {
                if (++guard > SPIN_CAP) break;
                __builtin_amdgcn_s_sleep(1);
                if (v < (unsigned long long)t) v = aload64(myR + tid);
            }
        }
        __syncthreads();
        __asm__ volatile("" ::: "memory");
        // stage q_t (agent) + r (agent)
        {
            const unsigned long long* src =
                (const unsigned long long*)(outh) + ((size_t)b0 * HLEN + t) * 256;
#pragma unroll
            for (int i = 0; i < 8; i++) {
                int idx = tid + i * 256;
                int bb = idx >> 8, j = idx & 255;
                float2 f = funpack2(aload64(src + (size_t)bb * HLEN * 256 + j));
                *(float2*)&qst[bb * CR16 + C16(2 * j)] = f;
            }
        }
        if (t > 0) {
            const unsigned long long* src = rrd + (size_t)b0 * 256;
            unsigned long long v[8];
#pragma unroll
            for (int i = 0; i < 8; i++) v[i] = aload64(src + tid + i * 256);
#pragma unroll
            for (int i = 0; i < 8; i++) {
                int idx = tid + i * 256;
                int bb = idx >> 8, j = idx & 255;
                float2 f = funpack2(v[i]);
                *(float2*)&rst[bb * CR16 + C16(2 * j)] = f;
            }
        }
        __syncthreads();
        // local GEMVs: a2 = Wh.q (+ Wr.r), tt = tanh(Wt.r)
        if (t > 0) {
#pragma unroll 1
            for (int b = 0; b < 8; b++) {
                const float* qb = &qst[b * CR16 + cc * 36];
                const float* rb = &rst[b * CR16 + cc * 36];
                float ah = 0.f, ar = 0.f, at = 0.f;
#pragma unroll
                for (int q = 0; q < 8; q++) {
                    float4 qv = *(const float4*)(qb + 4 * q);
                    float4 rv = *(const float4*)(rb + 4 * q);
                    float4 x = wh4[q], y = wr4[q], z = wt4[q];
                    ah += x.x * qv.x + x.y * qv.y + x.z * qv.z + x.w * qv.w;
                    ar += y.x * rv.x + y.y * rv.y + y.z * rv.z + y.w * rv.w;
                    at += z.x * rv.x + z.y * rv.y + z.z * rv.z + z.w * rv.w;
                }
                float a2v = ah + ar;
#pragma unroll
                for (int o = 1; o < 16; o <<= 1) {
                    a2v += __shfl_xor(a2v, o);
                    at  += __shfl_xor(at, o);
                }
                if (cc == 0) {
                    a2sl[rp * 9 + b] = a2v;
                    ttsl[rp * 9 + b] = tanhfast(at);
                }
            }
        } else {
#pragma unroll 1
            for (int b = 0; b < 8; b++) {
                const float* qb = &qst[b * CR16 + cc * 36];
                float ah = 0.f;
#pragma unroll
                for (int q = 0; q < 8; q++) {
                    float4 qv = *(const float4*)(qb + 4 * q);
                    float4 x = wh4[q];
                    ah += x.x * qv.x + x.y * qv.y + x.z * qv.z + x.w * qv.w;
                }
#pragma unroll
                for (int o = 1; o < 16; o <<= 1) ah += __shfl_xor(ah, o);
                if (cc == 0) {
                    a2sl[rp * 9 + b] = ah;
                    ttsl[rp * 9 + b] = 0.f;
                }
            }
        }
        __syncthreads();
        // local partial-s over all 128 p (thread: batch ab, p-quad aq)
        {
            float s4[4];
#pragma unroll
            for (int pi = 0; pi < 4; pi++) {
                float s = 0.f;
#pragma unroll
                for (int k = 0; k < 4; k++) {
                    float4 av = a1r[pi][k];
                    s += wvs[4 * k + 0] * tanhfast(av.x + a2sl[(4 * k + 0) * 9 + ab])
                       + wvs[4 * k + 1] * tanhfast(av.y + a2sl[(4 * k + 1) * 9 + ab])
                       + wvs[4 * k + 2] * tanhfast(av.z + a2sl[(4 * k + 2) * 9 + ab])
                       + wvs[4 * k + 3] * tanhfast(av.w + a2sl[(4 * k + 3) * 9 + ab]);
                }
                s4[pi] = s;
            }
            unsigned long long* d = sp + ((size_t)ug * 8 + ab) * 64 + aq * 2;
            astore64(d, fpack2(s4[0], s4[1]));
            astore64(d + 1, fpack2(s4[2], s4[3]));
        }
        __asm__ volatile("s_waitcnt vmcnt(0)" ::: "memory");
        __syncthreads();
        if (tid == 0) astore64(&myS[ug], (unsigned long long)(t + 1));

        // exchange 1: fan-in of 32 partials
        {
            if (tid < 32) {
                unsigned long long v = aload64(myS + tid);
                int guard = 0;
                while (!__all(v >= (unsigned long long)(t + 1))) {
                    if (++guard > SPIN_CAP) break;
                    __builtin_amdgcn_s_sleep(1);
                    if (v < (unsigned long long)(t + 1)) v = aload64(myS + tid);
                }
            }
            __syncthreads();
            __asm__ volatile("" ::: "memory");
#pragma unroll
            for (int i = 0; i < 2; i++) {
                int idx = tid + i * 256;
                int b = idx >> 6, p2 = idx & 63;
                float sx = 0.f, sy = 0.f;
#pragma unroll 8
                for (int g = 0; g < 32; g++) {
                    float2 f = funpack2(aload64(sp + ((size_t)g * 8 + b) * 64 + p2));
                    sx += f.x; sy += f.y;
                }
                scst[b * 132 + 2 * p2] = sx;
                scst[b * 132 + 2 * p2 + 1] = sy;
            }
        }
        __syncthreads();
        // local softmax over 128 p per batch
        {
            const int bb = tid >> 5, j = tid & 31;
            float4 v = *(float4*)&scst[bb * 132 + j * 4];
            float mx = fmaxf(fmaxf(v.x, v.y), fmaxf(v.z, v.w));
#pragma unroll
            for (int o = 1; o < 32; o <<= 1) mx = fmaxf(mx, __shfl_xor(mx, o));
            float ex = __expf(v.x - mx), ey = __expf(v.y - mx);
            float ez = __expf(v.z - mx), ew = __expf(v.w - mx);
            float ssum = (ex + ey) + (ez + ew);
#pragma unroll
            for (int o = 1; o < 32; o <<= 1) ssum += __shfl_xor(ssum, o);
            float inv = 1.0f / ssum;
            float4 sc4 = make_float4(ex * inv, ey * inv, ez * inv, ew * inv);
            *(float4*)&scst[bb * 132 + j * 4] = sc4;
        }
        __syncthreads();
        // r-update: outp from LLC (agent), split p-range over all 256 threads
        {
            const int ph = tid >> 7, pair = tid & 127;
            const int b2 = pair >> 4, u2 = pair & 15;
            float acc = (ph == 0) ? ttsl[u2 * 9 + b2] : 0.f;
            const float* opb = outp + ((size_t)(b0 + b2) * PLEN + ph * 64) * HDIM + u0 + u2;
#pragma unroll 8
            for (int p = 0; p < 64; p++)
                acc += scst[b2 * 132 + ph * 64 + p] * aload32f(opb + (size_t)p * HDIM);
            psum[tid] = acc;
        }
        __syncthreads();
        if (tid < 128) {
            float acc = psum[tid] + psum[tid + 128];
            float pr = __shfl_xor(acc, 1);
            if ((uuc & 1) == 0)
                astore64(rwr + (size_t)(b0 + bbc) * 256 + (u0 + uuc) / 2, fpack2(acc, pr));
        }
        __asm__ volatile("s_waitcnt vmcnt(0)" ::: "memory");
        __syncthreads();
        if (tid == 0) astore64(&myR[ug], (unsigned long long)(t + 1));
    }
}

// ---------------------------------------------------------------------------
// final: rep = tanh(r.fc1^T + b1 + hn.fc2^T + b2); out = rep.fc3^T + b3
__global__ __launch_bounds__(256) void final_kernel(
    const unsigned long long* __restrict__ r2, const float* __restrict__ outh,
    const float* __restrict__ fc1w, const float* __restrict__ fc1b,
    const float* __restrict__ fc2w, const float* __restrict__ fc2b,
    const float* __restrict__ fc3w, const float* __restrict__ fc3b,
    float* __restrict__ out)
{
    int b = blockIdx.x, tid = threadIdx.x;
    __shared__ float rs[HDIM], hs[HDIM], rep[HDIM], red[256];
    {
        float2 f = funpack2(r2[(size_t)b * 256 + tid]);
        rs[2 * tid] = f.x; rs[2 * tid + 1] = f.y;
    }
    for (int i = tid; i < 128; i += 256)
        ((float4*)hs)[i] = ((const float4*)(outh + ((size_t)(b * HLEN + HLEN - 1)) * HDIM))[i];
    __syncthreads();
    for (int u = tid; u < HDIM; u += 256) {
        const float4* w1 = (const float4*)(fc1w + (size_t)u * HDIM);
        const float4* w2 = (const float4*)(fc2w + (size_t)u * HDIM);
        float a = 0.f, bacc = 0.f;
        for (int k = 0; k < 128; k++) {
            float4 rv = ((float4*)rs)[k], hv = ((float4*)hs)[k];
            float4 x = w1[k]; a    += rv.x * x.x + rv.y * x.y + rv.z * x.z + rv.w * x.w;
            float4 y = w2[k]; bacc += hv.x * y.x + hv.y * y.y + hv.z * y.z + hv.w * y.w;
        }
        rep[u] = tanhfast(a + fc1b[u] + bacc + fc2b[u]);
    }
    __syncthreads();
    for (int cix = 0; cix < NCLS; cix++) {
        red[tid] = rep[tid] * fc3w[(size_t)cix * HDIM + tid]
                 + rep[tid + 256] * fc3w[(size_t)cix * HDIM + tid + 256];
        __syncthreads();
        for (int off = 128; off; off >>= 1) {
            if (tid < off) red[tid] += red[tid + off];
            __syncthreads();
        }
        if (tid == 0) out[b * NCLS + cix] = red[0] + fc3b[cix];
        __syncthreads();
    }
}

// ---------------------------------------------------------------------------
extern "C" void kernel_launch(void* const* d_in, const int* in_sizes, int n_in,
                              void* d_out, int out_size, void* d_ws, size_t ws_size,
                              hipStream_t stream)
{
    const int*   premise = (const int*)d_in[0];
    const int*   hyp     = (const int*)d_in[1];
    const float* emb     = (const float*)d_in[2];
    const float* Wih1    = (const float*)d_in[3];
    const float* Whh1    = (const float*)d_in[4];
    const float* bih1    = (const float*)d_in[5];
    const float* bhh1    = (const float*)d_in[6];
    const float* Wih2    = (const float*)d_in[7];
    const float* Whh2    = (const float*)d_in[8];
    const float* bih2    = (const float*)d_in[9];
    const float* bhh2    = (const float*)d_in[10];
    const float* Wy      = (const float*)d_in[11];
    const float* Wh      = (const float*)d_in[12];
    const float* Wr      = (const float*)d_in[13];
    const float* Wt      = (const float*)d_in[14];
    const float* wv      = (const float*)d_in[15];
    const float* fc1w    = (const float*)d_in[16];
    const float* fc1b    = (const float*)d_in[17];
    const float* fc2w    = (const float*)d_in[18];
    const float* fc2b    = (const float*)d_in[19];
    const float* fc3w    = (const float*)d_in[20];
    const float* fc3b    = (const float*)d_in[21];
    float* out = (float*)d_out;

    float* ws = (float*)d_ws;
    size_t off = 0;
    float* xp    = ws + off; off += (size_t)BSZ * PLEN * G4;
    float* xh    = ws + off; off += (size_t)BSZ * HLEN * G4;
    float* outp  = ws + off; off += (size_t)BSZ * PLEN * HDIM;
    float* outhp = ws + off; off += (size_t)BSZ * HLEN * HDIM;
    float* a1b   = ws + off; off += (size_t)BSZ * HDIM * PLEN;   // [b][p][h]
    unsigned long long* tbase = (unsigned long long*)(ws + off);
    unsigned long long* hAb   = tbase;                    // 16384 each (64*256)
    unsigned long long* hBb   = tbase + 16384;
    unsigned long long* hCb   = tbase + 2 * 16384;
    unsigned long long* hDb   = tbase + 3 * 16384;
    unsigned long long* rAtt  = tbase + 4 * 16384;        // att r buffers (own)
    unsigned long long* rBtt  = tbase + 5 * 16384;
    unsigned long long* sPart = tbase + 6 * 16384;        // 2*8*16384 = 262144
    unsigned long long* dnH   = sPart + 262144;           // 256 each
    unsigned long long* dnS   = dnH + 256;
    unsigned long long* dnR   = dnS + 256;
    off += (size_t)(6 * 16384 + 262144 + 768) * 2;        // in floats
    if (ws_size < off * sizeof(float)) return;

    // zero the done words (768 u64 = 3 * 256)
    ws_zero<<<dim3(3), dim3(256), 0, stream>>>(dnH);

    // input projections (biases folded in): 32x64 tiles
    proj_kernel<<<dim3(BSZ * PLEN / 32, G4 / 64), dim3(256), 0, stream>>>(
        premise, emb, Wih1, bih1, bhh1, xp);
    proj_kernel<<<dim3(BSZ * HLEN / 32, G4 / 64), dim3(256), 0, stream>>>(
        hyp, emb, Wih2, bih2, bhh2, xh);

    // fused persistent LSTM + attention (overlapped), 512 blocks, 43.3KB LDS
    fused_coop<<<dim3(512), dim3(256), 43328, stream>>>(
        xp, xh, Whh1, Whh2, outp, outhp,
        hAb, hBb, hCb, hDb, dnH,
        a1b, Wh, Wr, Wt, Wy, wv,
        rAtt, rBtt, sPart, dnS, dnR);

    // final classifier: r after step 63 lives in rB (63 & 1 == 1) = rBtt
    final_kernel<<<dim3(BSZ), dim3(256), 0, stream>>>(
        rBtt, outhp, fc1w, fc1b, fc2w, fc2b, fc3w, fc3b, out);
}